// Round 15
// baseline (211.632 us; speedup 1.0000x reference)
//
#include <hip/hip_runtime.h>
#include <hip/hip_fp16.h>

typedef short short8 __attribute__((ext_vector_type(8)));
typedef _Float16 half8 __attribute__((ext_vector_type(8)));
typedef float f32x4 __attribute__((ext_vector_type(4)));

#define N_NODES 100000
#define N_A     50000
#define N_EDGES 500000
#define N_T     4
#define D_IN    128
#define HF      128
#define BCOLS   144                  // 128 ft cols + 4 el + 4 er + 8 zero pad
#define TN      (N_T * N_NODES)
#define TE      (N_T * N_EDGES)
#define NB1     ((TN + 1023) / 1024) // 391 scan blocks
#define TILE_E  (BCOLS * D_IN)       // 18432 elems = 36864 B per (t) B-tile
#define LOG2E   1.44269504088896340736f
#define NPROJB  1563
#define EPB     1280                 // hist edges per proj block (5/thread)

__device__ __forceinline__ unsigned short f2b(float f) {
  unsigned int u = __float_as_uint(f);
  u += 0x7FFFu + ((u >> 16) & 1u);
  return (unsigned short)(u >> 16);
}
// f32 pair -> packed f16 word (v_cvt_pkrtz_f16_f32, 1 instruction)
__device__ __forceinline__ unsigned int pkh(float lo, float hi) {
  auto v = __builtin_amdgcn_cvt_pkrtz(lo, hi);
  unsigned int u; __builtin_memcpy(&u, &v, 4); return u;
}
__device__ __forceinline__ unsigned short f2h(float f) {
  auto v = __builtin_amdgcn_cvt_pkrtz(f, 0.f);
  unsigned int u; __builtin_memcpy(&u, &v, 4); return (unsigned short)(u & 0xFFFFu);
}
__device__ __forceinline__ __half2 w2h(unsigned int u) {
  __half2 h; __builtin_memcpy(&h, &u, 4); return h;
}
__device__ __forceinline__ unsigned int h2w(__half2 h) {
  unsigned int u; __builtin_memcpy(&u, &h, 4); return u;
}

// K0: fused prep. Blocks 0-1: Bt[t][144][128] bf16 (proj MFMA B-side),
// XOR-swizzled ((j*128+k) ^ ((j&7)<<3)); rows 128..135 = W@attn_{l,r}
// PRE-SCALED by log2(e). Blocks 2-33: WmT in F16 (permuted-k merge weights).
__global__ __launch_bounds__(256) void k_prep(const float* __restrict__ W,
    const float* __restrict__ al, const float* __restrict__ ar,
    const float* __restrict__ Wm,
    unsigned short* __restrict__ Bt, unsigned short* __restrict__ WmT)
{
  if (blockIdx.x < 2) {
    int idx = blockIdx.x * 256 + threadIdx.x;
    int t = idx >> 7, k = idx & 127;
    const float* Wr = W + ((size_t)t * D_IN + k) * HF;
    unsigned short* o = Bt + (size_t)t * TILE_E;
    for (int j = 0; j < HF; ++j)
      o[(j * D_IN + k) ^ ((j & 7) << 3)] = f2b(Wr[j]);
    for (int h = 0; h < 4; ++h) {
      float sl = 0.f, sr = 0.f;
      const float* alh = al + (t * 4 + h) * 32;
      const float* arh = ar + (t * 4 + h) * 32;
      for (int f = 0; f < 32; ++f) { float w = Wr[h * 32 + f]; sl += w * alh[f]; sr += w * arh[f]; }
      int jl = 128 + h, jr = 132 + h;
      o[(jl * D_IN + k) ^ ((jl & 7) << 3)] = f2b(sl * LOG2E);
      o[(jr * D_IN + k) ^ ((jr & 7) << 3)] = f2b(sr * LOG2E);
    }
    for (int j = 136; j < 144; ++j)
      o[(j * D_IN + k) ^ ((j & 7) << 3)] = 0;
  } else {
    int idx = (blockIdx.x - 2) * 256 + threadIdx.x;
    int kidx = idx >> 5, j = idx & 31;
    int slot = kidx >> 7, p = kidx & 127;
    int col = (p & 7) * 16 + (p >> 3);
    WmT[j * 256 + kidx] = f2h(Wm[(slot * 128 + col) * 32 + j]);
  }
}

// K1: projection GEMM + TAIL-FUSED edge histogram. 1563 blocks, 4 waves.
// Each block: (a) proj for 64 node rows (proven round-6 shape), then
// (b) hist for its 1280-edge chunk. Early-finishing blocks' hist tails
// overlap late blocks' proj work -> atomic latency hidden, no extra
// scheduling waves, no LDS-starved tiny blocks (round-14 lesson).
__global__ __launch_bounds__(256, 4) void k_projhist(const float* __restrict__ feat,
    const unsigned short* __restrict__ Btg,
    unsigned short* __restrict__ ftg,
    float* __restrict__ elg, float* __restrict__ erg,
    const int* __restrict__ dst, int* __restrict__ cnt, int* __restrict__ rank)
{
  __shared__ __align__(16) unsigned short Bs[TILE_E];      // 36.8 KB -> 4 blocks/CU
  const int tid = threadIdx.x;
  const int wave = tid >> 6, lane = tid & 63;
  const int l15 = lane & 15, g = lane >> 4;
  const int wrow0 = blockIdx.x * 64 + wave * 16;

  short8 a[4];
  {
    int row = wrow0 + l15;
    const float* fr = feat + (size_t)(row < N_NODES ? row : N_NODES - 1) * D_IN;
#pragma unroll
    for (int kt = 0; kt < 4; ++kt) {
      float4 v0 = *(const float4*)(fr + kt * 32 + g * 8);
      float4 v1 = *(const float4*)(fr + kt * 32 + g * 8 + 4);
      short8 s;
      s[0] = (short)f2b(v0.x); s[1] = (short)f2b(v0.y);
      s[2] = (short)f2b(v0.z); s[3] = (short)f2b(v0.w);
      s[4] = (short)f2b(v1.x); s[5] = (short)f2b(v1.y);
      s[6] = (short)f2b(v1.z); s[7] = (short)f2b(v1.w);
      a[kt] = s;
    }
  }

  for (int t = 0; t < N_T; ++t) {
    if (t > 0) __syncthreads();
    {
      const uint4* src = (const uint4*)(Btg + (size_t)t * TILE_E);
      uint4* dstv = (uint4*)Bs;
#pragma unroll
      for (int i = 0; i < 9; ++i)
        dstv[i * 256 + tid] = src[i * 256 + tid];
    }
    __syncthreads();

    f32x4 acc[8];
#pragma unroll
    for (int ct = 0; ct < 8; ++ct) {
      f32x4 c = {0.f, 0.f, 0.f, 0.f};
#pragma unroll
      for (int kt = 0; kt < 4; ++kt) {
        int row = ct * 16 + l15;
        int boff = (row * 256 + kt * 64 + g * 16) ^ ((l15 & 7) << 4);
        short8 b = *(const short8*)((const char*)Bs + boff);
        c = __builtin_amdgcn_mfma_f32_16x16x32_bf16(a[kt], b, c, 0, 0, 0);
      }
      acc[ct] = c;
    }
    {
      f32x4 c8 = {0.f, 0.f, 0.f, 0.f};
#pragma unroll
      for (int kt = 0; kt < 4; ++kt) {
        int row = 128 + l15;
        int boff = (row * 256 + kt * 64 + g * 16) ^ ((l15 & 7) << 4);
        short8 b = *(const short8*)((const char*)Bs + boff);
        c8 = __builtin_amdgcn_mfma_f32_16x16x32_bf16(a[kt], b, c8, 0, 0, 0);
      }
      if (l15 < 8) {
#pragma unroll
        for (int r = 0; r < 4; ++r) {
          int row = wrow0 + g * 4 + r;
          if (row < N_NODES) {
            float v = c8[r];
            if (l15 < 4) elg[((size_t)t * N_NODES + row) * 4 + l15] = v;
            else         erg[((size_t)t * N_NODES + row) * 4 + (l15 - 4)] = v;
          }
        }
      }
    }
    // direct permuted ft store (F16): row-position p = l15*8 + ct
#pragma unroll
    for (int r = 0; r < 4; ++r) {
      int row = wrow0 + g * 4 + r;
      if (row < N_NODES) {
        uint4 o;
        o.x = pkh(acc[0][r], acc[1][r]);
        o.y = pkh(acc[2][r], acc[3][r]);
        o.z = pkh(acc[4][r], acc[5][r]);
        o.w = pkh(acc[6][r], acc[7][r]);
        *(uint4*)(ftg + ((size_t)t * N_NODES + row) * HF + l15 * 8) = o;
      }
    }
  }

  // ---- hist tail: this block's 1280-edge chunk (5 edges/thread) ----
  int base_e = blockIdx.x * EPB;
#pragma unroll
  for (int k = 0; k < EPB / 256; ++k) {
    int idx = base_e + k * 256 + tid;
    if (idx < TE) {
      int t = idx / N_EDGES;
      int d = dst[idx];
      bool keep = (t < 2) ? (d < N_A) : (d >= N_A);
      if (keep) rank[idx] = atomicAdd(&cnt[t * N_NODES + d], 1);
    }
  }
}

__global__ __launch_bounds__(256) void k_scan1(const int* __restrict__ cnt,
    int* __restrict__ ofs, int* __restrict__ bsum) {
  __shared__ int ts[256];
  int b = blockIdx.x, t = threadIdx.x;
  int base = b * 1024 + t * 4;
  int v0 = 0, v1 = 0, v2 = 0, v3 = 0;
  if (base + 0 < TN) v0 = cnt[base + 0];
  if (base + 1 < TN) v1 = cnt[base + 1];
  if (base + 2 < TN) v2 = cnt[base + 2];
  if (base + 3 < TN) v3 = cnt[base + 3];
  int s = v0 + v1 + v2 + v3;
  ts[t] = s;
  __syncthreads();
  for (int o = 1; o < 256; o <<= 1) {
    int x = (t >= o) ? ts[t - o] : 0;
    __syncthreads();
    ts[t] += x;
    __syncthreads();
  }
  int run = ts[t] - s;
  if (base + 0 < TN) ofs[base + 0] = run; run += v0;
  if (base + 1 < TN) ofs[base + 1] = run; run += v1;
  if (base + 2 < TN) ofs[base + 2] = run; run += v2;
  if (base + 3 < TN) ofs[base + 3] = run;
  if (t == 255) bsum[b] = ts[255];
}

__global__ __launch_bounds__(512) void k_scan2(int* __restrict__ bsum) {
  __shared__ int ts[512];
  int t = threadIdx.x;
  int v = (t < NB1) ? bsum[t] : 0;
  ts[t] = v;
  __syncthreads();
  for (int o = 1; o < 512; o <<= 1) {
    int x = (t >= o) ? ts[t - o] : 0;
    __syncthreads();
    ts[t] += x;
    __syncthreads();
  }
  if (t < NB1) bsum[t] = ts[t] - v;
}

// K3: slim scatter: 4 B record = src ft-row index; position from ofs+bsum+rank.
__global__ __launch_bounds__(256) void k_scatter(const int* __restrict__ src, const int* __restrict__ dst,
    const int* __restrict__ ofs, const int* __restrict__ bsum, const int* __restrict__ rank,
    int* __restrict__ bkt) {
  int idx = blockIdx.x * 256 + threadIdx.x;
  if (idx >= TE) return;
  int t = idx / N_EDGES;
  int d = dst[idx];
  bool keep = (t < 2) ? (d < N_A) : (d >= N_A);
  if (!keep) return;
  int key = t * N_NODES + d;
  int p = ofs[key] + bsum[key >> 10] + rank[idx];
  bkt[p] = t * N_NODES + src[idx];
}

// K4: gather. 8 pairs/wave, 8 lanes/pair, MASKED UNROLL-4: 16 loads in
// flight per iteration (4 records + 4 el + 8 ft rows); invalid edges clamp
// to index i (valid) with weight forced to 0. f16 __hfma2 accumulation.
__global__ __launch_bounds__(256) void k_gather(const int* __restrict__ bkt,
    const int* __restrict__ ofs, const int* __restrict__ cnt, const int* __restrict__ bsum,
    const float* __restrict__ elg, const float* __restrict__ erg,
    const uint4* __restrict__ ftu, uint4* __restrict__ aggb)
{
  int wid = blockIdx.x * 4 + (threadIdx.x >> 6);
  int lane = threadIdx.x & 63;
  int g8 = lane >> 3, l7 = lane & 7;
  int pid = wid * 8 + g8;                      // pair id = node*2 + slot
  int n = pid >> 1, slot = pid & 1;
  int t = slot + ((n >= N_A) ? 2 : 0);
  int key = t * N_NODES + n;
  int base = ofs[key] + bsum[key >> 10];
  int c = cnt[key];
  float4 er4 = *(const float4*)(erg + (size_t)key * 4);
  __half2 A0 = __float2half2_rn(0.f), A1 = A0, A2 = A0, A3 = A0;
  __half2 B0 = A0, B1 = A0, B2 = A0, B3 = A0;
  float d0 = 0.f, d1 = 0.f, d2 = 0.f, d3 = 0.f;
  int qb = l7 * 2;
  for (int i = 0; i < c; i += 4) {
    bool v1 = i + 1 < c, v2 = i + 2 < c, v3 = i + 3 < c;
    int e0 = base + i;
    int e1 = base + (v1 ? i + 1 : i);
    int e2 = base + (v2 ? i + 2 : i);
    int e3 = base + (v3 ? i + 3 : i);
    int s0 = bkt[e0], s1 = bkt[e1], s2 = bkt[e2], s3 = bkt[e3];
    float4 eA = *(const float4*)(elg + (size_t)s0 * 4);
    float4 eB = *(const float4*)(elg + (size_t)s1 * 4);
    float4 eC = *(const float4*)(elg + (size_t)s2 * 4);
    float4 eD = *(const float4*)(elg + (size_t)s3 * 4);
    uint4 u0a = ftu[(size_t)s0 * 16 + qb], u0b = ftu[(size_t)s0 * 16 + qb + 1];
    uint4 u1a = ftu[(size_t)s1 * 16 + qb], u1b = ftu[(size_t)s1 * 16 + qb + 1];
    uint4 u2a = ftu[(size_t)s2 * 16 + qb], u2b = ftu[(size_t)s2 * 16 + qb + 1];
    uint4 u3a = ftu[(size_t)s3 * 16 + qb], u3b = ftu[(size_t)s3 * 16 + qb + 1];
    float s;
    float wa0, wa1, wa2, wa3, wb0, wb1, wb2, wb3;
    float wc0, wc1, wc2, wc3, wd0, wd1, wd2, wd3;
    s = eA.x + er4.x; wa0 = exp2f(fmaxf(s, 0.2f * s));
    s = eA.y + er4.y; wa1 = exp2f(fmaxf(s, 0.2f * s));
    s = eA.z + er4.z; wa2 = exp2f(fmaxf(s, 0.2f * s));
    s = eA.w + er4.w; wa3 = exp2f(fmaxf(s, 0.2f * s));
    s = eB.x + er4.x; wb0 = exp2f(fmaxf(s, 0.2f * s));
    s = eB.y + er4.y; wb1 = exp2f(fmaxf(s, 0.2f * s));
    s = eB.z + er4.z; wb2 = exp2f(fmaxf(s, 0.2f * s));
    s = eB.w + er4.w; wb3 = exp2f(fmaxf(s, 0.2f * s));
    s = eC.x + er4.x; wc0 = exp2f(fmaxf(s, 0.2f * s));
    s = eC.y + er4.y; wc1 = exp2f(fmaxf(s, 0.2f * s));
    s = eC.z + er4.z; wc2 = exp2f(fmaxf(s, 0.2f * s));
    s = eC.w + er4.w; wc3 = exp2f(fmaxf(s, 0.2f * s));
    s = eD.x + er4.x; wd0 = exp2f(fmaxf(s, 0.2f * s));
    s = eD.y + er4.y; wd1 = exp2f(fmaxf(s, 0.2f * s));
    s = eD.z + er4.z; wd2 = exp2f(fmaxf(s, 0.2f * s));
    s = eD.w + er4.w; wd3 = exp2f(fmaxf(s, 0.2f * s));
    if (!v1) { wb0 = wb1 = wb2 = wb3 = 0.f; }
    if (!v2) { wc0 = wc1 = wc2 = wc3 = 0.f; }
    if (!v3) { wd0 = wd1 = wd2 = wd3 = 0.f; }
    d0 += wa0 + wb0 + wc0 + wd0;
    d1 += wa1 + wb1 + wc1 + wd1;
    d2 += wa2 + wb2 + wc2 + wd2;
    d3 += wa3 + wb3 + wc3 + wd3;
    __half2 h0, h1, h2, h3;
    h0 = __float2half2_rn(wa0); h1 = __float2half2_rn(wa1);
    h2 = __float2half2_rn(wa2); h3 = __float2half2_rn(wa3);
    A0 = __hfma2(w2h(u0a.x), h0, A0); A1 = __hfma2(w2h(u0a.y), h1, A1);
    A2 = __hfma2(w2h(u0a.z), h2, A2); A3 = __hfma2(w2h(u0a.w), h3, A3);
    B0 = __hfma2(w2h(u0b.x), h0, B0); B1 = __hfma2(w2h(u0b.y), h1, B1);
    B2 = __hfma2(w2h(u0b.z), h2, B2); B3 = __hfma2(w2h(u0b.w), h3, B3);
    h0 = __float2half2_rn(wb0); h1 = __float2half2_rn(wb1);
    h2 = __float2half2_rn(wb2); h3 = __float2half2_rn(wb3);
    A0 = __hfma2(w2h(u1a.x), h0, A0); A1 = __hfma2(w2h(u1a.y), h1, A1);
    A2 = __hfma2(w2h(u1a.z), h2, A2); A3 = __hfma2(w2h(u1a.w), h3, A3);
    B0 = __hfma2(w2h(u1b.x), h0, B0); B1 = __hfma2(w2h(u1b.y), h1, B1);
    B2 = __hfma2(w2h(u1b.z), h2, B2); B3 = __hfma2(w2h(u1b.w), h3, B3);
    h0 = __float2half2_rn(wc0); h1 = __float2half2_rn(wc1);
    h2 = __float2half2_rn(wc2); h3 = __float2half2_rn(wc3);
    A0 = __hfma2(w2h(u2a.x), h0, A0); A1 = __hfma2(w2h(u2a.y), h1, A1);
    A2 = __hfma2(w2h(u2a.z), h2, A2); A3 = __hfma2(w2h(u2a.w), h3, A3);
    B0 = __hfma2(w2h(u2b.x), h0, B0); B1 = __hfma2(w2h(u2b.y), h1, B1);
    B2 = __hfma2(w2h(u2b.z), h2, B2); B3 = __hfma2(w2h(u2b.w), h3, B3);
    h0 = __float2half2_rn(wd0); h1 = __float2half2_rn(wd1);
    h2 = __float2half2_rn(wd2); h3 = __float2half2_rn(wd3);
    A0 = __hfma2(w2h(u3a.x), h0, A0); A1 = __hfma2(w2h(u3a.y), h1, A1);
    A2 = __hfma2(w2h(u3a.z), h2, A2); A3 = __hfma2(w2h(u3a.w), h3, A3);
    B0 = __hfma2(w2h(u3b.x), h0, B0); B1 = __hfma2(w2h(u3b.y), h1, B1);
    B2 = __hfma2(w2h(u3b.z), h2, B2); B3 = __hfma2(w2h(u3b.w), h3, B3);
  }
  __half2 i0 = __float2half2_rn((c > 0) ? 1.f / d0 : 0.f);
  __half2 i1 = __float2half2_rn((c > 0) ? 1.f / d1 : 0.f);
  __half2 i2 = __float2half2_rn((c > 0) ? 1.f / d2 : 0.f);
  __half2 i3 = __float2half2_rn((c > 0) ? 1.f / d3 : 0.f);
  uint4 oA, oB;
  oA.x = h2w(__hmul2(A0, i0)); oA.y = h2w(__hmul2(A1, i1));
  oA.z = h2w(__hmul2(A2, i2)); oA.w = h2w(__hmul2(A3, i3));
  oB.x = h2w(__hmul2(B0, i0)); oB.y = h2w(__hmul2(B1, i1));
  oB.z = h2w(__hmul2(B2, i2)); oB.w = h2w(__hmul2(B3, i3));
  size_t ob = (size_t)n * 32 + slot * 16 + qb;
  aggb[ob] = oA;
  aggb[ob + 1] = oB;
}

// K5: merge GEMM via F16 MFMA. 64 nodes/block, out = agg(f16, permuted-k) @ WmT + bm.
__global__ __launch_bounds__(256) void k_merge(const unsigned short* __restrict__ aggb,
    const unsigned short* __restrict__ WmT, const float* __restrict__ bm,
    float* __restrict__ out)
{
  __shared__ __align__(16) unsigned short Al[64 * 264];
  __shared__ __align__(16) unsigned short Bl[32 * 264];
  int n0 = blockIdx.x * 64;
  int tid = threadIdx.x;
  const uint4* asrc = (const uint4*)(aggb + (size_t)n0 * 256);
  for (int i = tid; i < 2048; i += 256) {
    int r = i >> 5, c = i & 31;
    *(uint4*)&Al[r * 264 + c * 8] = asrc[r * 32 + c];
  }
  for (int i = tid; i < 1024; i += 256) {
    int r = i >> 5, c = i & 31;
    *(uint4*)&Bl[r * 264 + c * 8] = ((const uint4*)WmT)[r * 32 + c];
  }
  __syncthreads();
  int wave = tid >> 6, lane = tid & 63;
  int l15 = lane & 15, lk = (lane >> 4) * 8;
  half8 a[8];
#pragma unroll
  for (int kt = 0; kt < 8; ++kt)
    a[kt] = *(const half8*)&Al[(wave * 16 + l15) * 264 + kt * 32 + lk];
  f32x4 acc0 = {0.f, 0.f, 0.f, 0.f}, acc1 = {0.f, 0.f, 0.f, 0.f};
#pragma unroll
  for (int kt = 0; kt < 8; ++kt) {
    half8 b0 = *(const half8*)&Bl[l15 * 264 + kt * 32 + lk];
    half8 b1 = *(const half8*)&Bl[(16 + l15) * 264 + kt * 32 + lk];
    acc0 = __builtin_amdgcn_mfma_f32_16x16x32_f16(a[kt], b0, acc0, 0, 0, 0);
    acc1 = __builtin_amdgcn_mfma_f32_16x16x32_f16(a[kt], b1, acc1, 0, 0, 0);
  }
  float bm0 = bm[l15], bm1 = bm[16 + l15];
#pragma unroll
  for (int r = 0; r < 4; ++r) {
    int row = n0 + wave * 16 + (lane >> 4) * 4 + r;
    if (row < N_NODES) {
      out[(size_t)row * 32 + l15] = acc0[r] + bm0;
      out[(size_t)row * 32 + 16 + l15] = acc1[r] + bm1;
    }
  }
}

extern "C" void kernel_launch(void* const* d_in, const int* in_sizes, int n_in,
                              void* d_out, int out_size, void* d_ws, size_t ws_size,
                              hipStream_t stream)
{
  const float* feat = (const float*)d_in[0];
  const int*   src  = (const int*)d_in[1];
  const int*   dst  = (const int*)d_in[2];
  const float* W    = (const float*)d_in[4];
  const float* al   = (const float*)d_in[5];
  const float* ar   = (const float*)d_in[6];
  const float* Wm   = (const float*)d_in[7];
  const float* bm   = (const float*)d_in[8];
  float* out = (float*)d_out;
  (void)in_sizes; (void)n_in; (void)out_size; (void)ws_size;

  char* w = (char*)d_ws;
  size_t o = 0;
  auto take = [&](size_t bytes) -> void* {
    void* p = w + o;
    o += (bytes + 255) & ~(size_t)255;
    return p;
  };
  unsigned short* Btg = (unsigned short*)take((size_t)N_T * TILE_E * 2);         // 147 KB
  unsigned short* WmT = (unsigned short*)take((size_t)32 * 256 * 2);             // 16 KB
  unsigned short* ftg = (unsigned short*)take((size_t)N_T * N_NODES * HF * 2);   // 102.4 MB
  float* elg   = (float*)take((size_t)N_T * N_NODES * 4 * 4);                    // 6.4 MB
  float* erg   = (float*)take((size_t)N_T * N_NODES * 4 * 4);                    // 6.4 MB
  int*   cntb  = (int*)take((size_t)TN * 4);                                     // 1.6 MB
  int*   ofs   = (int*)take((size_t)TN * 4);
  int*   bsum  = (int*)take(4096);
  int*   rank  = (int*)take((size_t)TE * 4);                                     // 8 MB
  int*   bkt   = (int*)take((size_t)TE * 4);                                     // 8 MB
  unsigned short* aggb = (unsigned short*)take((size_t)(N_NODES + 64) * 256 * 2);// 51.2 MB

  hipMemsetAsync(cntb, 0, (size_t)TN * 4, stream);

  k_prep<<<34, 256, 0, stream>>>(W, al, ar, Wm, Btg, WmT);
  k_projhist<<<NPROJB, 256, 0, stream>>>(feat, Btg, ftg, elg, erg, dst, cntb, rank);
  k_scan1<<<NB1, 256, 0, stream>>>(cntb, ofs, bsum);
  k_scan2<<<1, 512, 0, stream>>>(bsum);
  k_scatter<<<(TE + 255) / 256, 256, 0, stream>>>(src, dst, ofs, bsum, rank, bkt);
  k_gather<<<6250, 256, 0, stream>>>(bkt, ofs, cntb, bsum, elg, erg, (const uint4*)ftg, (uint4*)aggb);
  k_merge<<<1563, 256, 0, stream>>>(aggb, WmT, bm, out);
}

// Round 16
// 187.730 us; speedup vs baseline: 1.1273x; 1.1273x over previous
//
#include <hip/hip_runtime.h>
#include <hip/hip_fp16.h>

typedef short short8 __attribute__((ext_vector_type(8)));
typedef _Float16 half8 __attribute__((ext_vector_type(8)));
typedef float f32x4 __attribute__((ext_vector_type(4)));

#define N_NODES 100000
#define N_A     50000
#define N_EDGES 500000
#define N_T     4
#define D_IN    128
#define HF      128
#define BCOLS   144                  // 128 ft cols + 4 el + 4 er + 8 zero pad
#define TN      (N_T * N_NODES)
#define TE      (N_T * N_EDGES)
#define NB1     ((TN + 1023) / 1024) // 391 scan blocks
#define TILE_E  (BCOLS * D_IN)       // 18432 elems = 36864 B per (t) B-tile
#define LOG2E   1.44269504088896340736f

__device__ __forceinline__ unsigned short f2b(float f) {
  unsigned int u = __float_as_uint(f);
  u += 0x7FFFu + ((u >> 16) & 1u);
  return (unsigned short)(u >> 16);
}
// f32 pair -> packed f16 word (v_cvt_pkrtz_f16_f32, 1 instruction)
__device__ __forceinline__ unsigned int pkh(float lo, float hi) {
  auto v = __builtin_amdgcn_cvt_pkrtz(lo, hi);
  unsigned int u; __builtin_memcpy(&u, &v, 4); return u;
}
__device__ __forceinline__ unsigned short f2h(float f) {
  auto v = __builtin_amdgcn_cvt_pkrtz(f, 0.f);
  unsigned int u; __builtin_memcpy(&u, &v, 4); return (unsigned short)(u & 0xFFFFu);
}
__device__ __forceinline__ __half2 w2h(unsigned int u) {
  __half2 h; __builtin_memcpy(&h, &u, 4); return h;
}
__device__ __forceinline__ unsigned int h2w(__half2 h) {
  unsigned int u; __builtin_memcpy(&u, &h, 4); return u;
}

// K0: fused prep. Blocks 0-1: Bt[t][144][128] bf16 (proj MFMA B-side),
// XOR-swizzled ((j*128+k) ^ ((j&7)<<3)); rows 128..135 = W@attn_{l,r}
// PRE-SCALED by log2(e). Blocks 2-33: WmT in F16 (permuted-k merge weights).
__global__ __launch_bounds__(256) void k_prep(const float* __restrict__ W,
    const float* __restrict__ al, const float* __restrict__ ar,
    const float* __restrict__ Wm,
    unsigned short* __restrict__ Bt, unsigned short* __restrict__ WmT)
{
  if (blockIdx.x < 2) {
    int idx = blockIdx.x * 256 + threadIdx.x;
    int t = idx >> 7, k = idx & 127;
    const float* Wr = W + ((size_t)t * D_IN + k) * HF;
    unsigned short* o = Bt + (size_t)t * TILE_E;
    for (int j = 0; j < HF; ++j)
      o[(j * D_IN + k) ^ ((j & 7) << 3)] = f2b(Wr[j]);
    for (int h = 0; h < 4; ++h) {
      float sl = 0.f, sr = 0.f;
      const float* alh = al + (t * 4 + h) * 32;
      const float* arh = ar + (t * 4 + h) * 32;
      for (int f = 0; f < 32; ++f) { float w = Wr[h * 32 + f]; sl += w * alh[f]; sr += w * arh[f]; }
      int jl = 128 + h, jr = 132 + h;
      o[(jl * D_IN + k) ^ ((jl & 7) << 3)] = f2b(sl * LOG2E);
      o[(jr * D_IN + k) ^ ((jr & 7) << 3)] = f2b(sr * LOG2E);
    }
    for (int j = 136; j < 144; ++j)
      o[(j * D_IN + k) ^ ((j & 7) << 3)] = 0;
  } else {
    int idx = (blockIdx.x - 2) * 256 + threadIdx.x;
    int kidx = idx >> 5, j = idx & 31;
    int slot = kidx >> 7, p = kidx & 127;
    int col = (p & 7) * 16 + (p >> 3);
    WmT[j * 256 + kidx] = f2h(Wm[(slot * 128 + col) * 32 + j]);
  }
}

// K1: projection GEMM (proven round-6/13 shape). Block = 64 rows (4 waves x 16),
// grid 1563, launch_bounds(256,4). ft written in permuted layout as F16.
__global__ __launch_bounds__(256, 4) void k_proj(const float* __restrict__ feat,
    const unsigned short* __restrict__ Btg,
    unsigned short* __restrict__ ftg,
    float* __restrict__ elg, float* __restrict__ erg)
{
  __shared__ __align__(16) unsigned short Bs[TILE_E];      // 36.8 KB -> 4 blocks/CU
  const int tid = threadIdx.x;
  const int wave = tid >> 6, lane = tid & 63;
  const int l15 = lane & 15, g = lane >> 4;
  const int wrow0 = blockIdx.x * 64 + wave * 16;

  short8 a[4];
  {
    int row = wrow0 + l15;
    const float* fr = feat + (size_t)(row < N_NODES ? row : N_NODES - 1) * D_IN;
#pragma unroll
    for (int kt = 0; kt < 4; ++kt) {
      float4 v0 = *(const float4*)(fr + kt * 32 + g * 8);
      float4 v1 = *(const float4*)(fr + kt * 32 + g * 8 + 4);
      short8 s;
      s[0] = (short)f2b(v0.x); s[1] = (short)f2b(v0.y);
      s[2] = (short)f2b(v0.z); s[3] = (short)f2b(v0.w);
      s[4] = (short)f2b(v1.x); s[5] = (short)f2b(v1.y);
      s[6] = (short)f2b(v1.z); s[7] = (short)f2b(v1.w);
      a[kt] = s;
    }
  }

  for (int t = 0; t < N_T; ++t) {
    if (t > 0) __syncthreads();
    {
      const uint4* src = (const uint4*)(Btg + (size_t)t * TILE_E);
      uint4* dstv = (uint4*)Bs;
#pragma unroll
      for (int i = 0; i < 9; ++i)
        dstv[i * 256 + tid] = src[i * 256 + tid];
    }
    __syncthreads();

    f32x4 acc[8];
#pragma unroll
    for (int ct = 0; ct < 8; ++ct) {
      f32x4 c = {0.f, 0.f, 0.f, 0.f};
#pragma unroll
      for (int kt = 0; kt < 4; ++kt) {
        int row = ct * 16 + l15;
        int boff = (row * 256 + kt * 64 + g * 16) ^ ((l15 & 7) << 4);
        short8 b = *(const short8*)((const char*)Bs + boff);
        c = __builtin_amdgcn_mfma_f32_16x16x32_bf16(a[kt], b, c, 0, 0, 0);
      }
      acc[ct] = c;
    }
    {
      f32x4 c8 = {0.f, 0.f, 0.f, 0.f};
#pragma unroll
      for (int kt = 0; kt < 4; ++kt) {
        int row = 128 + l15;
        int boff = (row * 256 + kt * 64 + g * 16) ^ ((l15 & 7) << 4);
        short8 b = *(const short8*)((const char*)Bs + boff);
        c8 = __builtin_amdgcn_mfma_f32_16x16x32_bf16(a[kt], b, c8, 0, 0, 0);
      }
      if (l15 < 8) {
#pragma unroll
        for (int r = 0; r < 4; ++r) {
          int row = wrow0 + g * 4 + r;
          if (row < N_NODES) {
            float v = c8[r];
            if (l15 < 4) elg[((size_t)t * N_NODES + row) * 4 + l15] = v;
            else         erg[((size_t)t * N_NODES + row) * 4 + (l15 - 4)] = v;
          }
        }
      }
    }
    // direct permuted ft store (F16): row-position p = l15*8 + ct
#pragma unroll
    for (int r = 0; r < 4; ++r) {
      int row = wrow0 + g * 4 + r;
      if (row < N_NODES) {
        uint4 o;
        o.x = pkh(acc[0][r], acc[1][r]);
        o.y = pkh(acc[2][r], acc[3][r]);
        o.z = pkh(acc[4][r], acc[5][r]);
        o.w = pkh(acc[6][r], acc[7][r]);
        *(uint4*)(ftg + ((size_t)t * N_NODES + row) * HF + l15 * 8) = o;
      }
    }
  }
}

// K2: histogram of kept edges by (t,dst) + per-edge within-bucket rank
__global__ __launch_bounds__(256) void k_hist(const int* __restrict__ dst,
    int* __restrict__ cnt, int* __restrict__ rank) {
  int idx = blockIdx.x * 256 + threadIdx.x;
  if (idx >= TE) return;
  int t = idx / N_EDGES;
  int d = dst[idx];
  bool keep = (t < 2) ? (d < N_A) : (d >= N_A);
  if (keep) rank[idx] = atomicAdd(&cnt[t * N_NODES + d], 1);
}

__global__ __launch_bounds__(256) void k_scan1(const int* __restrict__ cnt,
    int* __restrict__ ofs, int* __restrict__ bsum) {
  __shared__ int ts[256];
  int b = blockIdx.x, t = threadIdx.x;
  int base = b * 1024 + t * 4;
  int v0 = 0, v1 = 0, v2 = 0, v3 = 0;
  if (base + 0 < TN) v0 = cnt[base + 0];
  if (base + 1 < TN) v1 = cnt[base + 1];
  if (base + 2 < TN) v2 = cnt[base + 2];
  if (base + 3 < TN) v3 = cnt[base + 3];
  int s = v0 + v1 + v2 + v3;
  ts[t] = s;
  __syncthreads();
  for (int o = 1; o < 256; o <<= 1) {
    int x = (t >= o) ? ts[t - o] : 0;
    __syncthreads();
    ts[t] += x;
    __syncthreads();
  }
  int run = ts[t] - s;
  if (base + 0 < TN) ofs[base + 0] = run; run += v0;
  if (base + 1 < TN) ofs[base + 1] = run; run += v1;
  if (base + 2 < TN) ofs[base + 2] = run; run += v2;
  if (base + 3 < TN) ofs[base + 3] = run;
  if (t == 255) bsum[b] = ts[255];
}

__global__ __launch_bounds__(512) void k_scan2(int* __restrict__ bsum) {
  __shared__ int ts[512];
  int t = threadIdx.x;
  int v = (t < NB1) ? bsum[t] : 0;
  ts[t] = v;
  __syncthreads();
  for (int o = 1; o < 512; o <<= 1) {
    int x = (t >= o) ? ts[t - o] : 0;
    __syncthreads();
    ts[t] += x;
    __syncthreads();
  }
  if (t < NB1) bsum[t] = ts[t] - v;
}

// K3: slim scatter: 4 B record = src ft-row index; position from ofs+bsum+rank.
__global__ __launch_bounds__(256) void k_scatter(const int* __restrict__ src, const int* __restrict__ dst,
    const int* __restrict__ ofs, const int* __restrict__ bsum, const int* __restrict__ rank,
    int* __restrict__ bkt) {
  int idx = blockIdx.x * 256 + threadIdx.x;
  if (idx >= TE) return;
  int t = idx / N_EDGES;
  int d = dst[idx];
  bool keep = (t < 2) ? (d < N_A) : (d >= N_A);
  if (!keep) return;
  int key = t * N_NODES + d;
  int p = ofs[key] + bsum[key >> 10] + rank[idx];
  bkt[p] = t * N_NODES + src[idx];
}

// K4: FUSED gather + merge. Block = 4 waves x 8 pairs = 16 consecutive nodes.
// Phase 1 (all waves): masked unroll-4 edge gather with f16 __hfma2 accum;
// results go to a 16x264 f16 LDS tile (node-row x permuted-k).
// Phase 2 (waves 0-1): 16x256x32 merge GEMM, B-frags straight from the
// L2-resident WmT; out written directly. aggb round-trip eliminated.
__global__ __launch_bounds__(256) void k_gathermerge(const int* __restrict__ bkt,
    const int* __restrict__ ofs, const int* __restrict__ cnt, const int* __restrict__ bsum,
    const float* __restrict__ elg, const float* __restrict__ erg,
    const uint4* __restrict__ ftu,
    const unsigned short* __restrict__ WmT, const float* __restrict__ bm,
    float* __restrict__ out)
{
  __shared__ __align__(16) unsigned short Al[16 * 264];    // 8.4 KB
  int tid = threadIdx.x;
  int wave = tid >> 6, lane = tid & 63;
  int g8 = lane >> 3, l7 = lane & 7;
  int pidl = wave * 8 + g8;                    // local pair 0..31
  int pid = blockIdx.x * 32 + pidl;            // pair id = node*2 + slot
  int n = pid >> 1, slot = pid & 1;
  int t = slot + ((n >= N_A) ? 2 : 0);
  int key = t * N_NODES + n;
  int base = ofs[key] + bsum[key >> 10];
  int c = cnt[key];
  float4 er4 = *(const float4*)(erg + (size_t)key * 4);
  __half2 A0 = __float2half2_rn(0.f), A1 = A0, A2 = A0, A3 = A0;
  __half2 B0 = A0, B1 = A0, B2 = A0, B3 = A0;
  float d0 = 0.f, d1 = 0.f, d2 = 0.f, d3 = 0.f;
  int qb = l7 * 2;
  for (int i = 0; i < c; i += 4) {
    bool v1 = i + 1 < c, v2 = i + 2 < c, v3 = i + 3 < c;
    int e0 = base + i;
    int e1 = base + (v1 ? i + 1 : i);
    int e2 = base + (v2 ? i + 2 : i);
    int e3 = base + (v3 ? i + 3 : i);
    int s0 = bkt[e0], s1 = bkt[e1], s2 = bkt[e2], s3 = bkt[e3];
    float4 eA = *(const float4*)(elg + (size_t)s0 * 4);
    float4 eB = *(const float4*)(elg + (size_t)s1 * 4);
    float4 eC = *(const float4*)(elg + (size_t)s2 * 4);
    float4 eD = *(const float4*)(elg + (size_t)s3 * 4);
    uint4 u0a = ftu[(size_t)s0 * 16 + qb], u0b = ftu[(size_t)s0 * 16 + qb + 1];
    uint4 u1a = ftu[(size_t)s1 * 16 + qb], u1b = ftu[(size_t)s1 * 16 + qb + 1];
    uint4 u2a = ftu[(size_t)s2 * 16 + qb], u2b = ftu[(size_t)s2 * 16 + qb + 1];
    uint4 u3a = ftu[(size_t)s3 * 16 + qb], u3b = ftu[(size_t)s3 * 16 + qb + 1];
    float s;
    float wa0, wa1, wa2, wa3, wb0, wb1, wb2, wb3;
    float wc0, wc1, wc2, wc3, wd0, wd1, wd2, wd3;
    s = eA.x + er4.x; wa0 = exp2f(fmaxf(s, 0.2f * s));
    s = eA.y + er4.y; wa1 = exp2f(fmaxf(s, 0.2f * s));
    s = eA.z + er4.z; wa2 = exp2f(fmaxf(s, 0.2f * s));
    s = eA.w + er4.w; wa3 = exp2f(fmaxf(s, 0.2f * s));
    s = eB.x + er4.x; wb0 = exp2f(fmaxf(s, 0.2f * s));
    s = eB.y + er4.y; wb1 = exp2f(fmaxf(s, 0.2f * s));
    s = eB.z + er4.z; wb2 = exp2f(fmaxf(s, 0.2f * s));
    s = eB.w + er4.w; wb3 = exp2f(fmaxf(s, 0.2f * s));
    s = eC.x + er4.x; wc0 = exp2f(fmaxf(s, 0.2f * s));
    s = eC.y + er4.y; wc1 = exp2f(fmaxf(s, 0.2f * s));
    s = eC.z + er4.z; wc2 = exp2f(fmaxf(s, 0.2f * s));
    s = eC.w + er4.w; wc3 = exp2f(fmaxf(s, 0.2f * s));
    s = eD.x + er4.x; wd0 = exp2f(fmaxf(s, 0.2f * s));
    s = eD.y + er4.y; wd1 = exp2f(fmaxf(s, 0.2f * s));
    s = eD.z + er4.z; wd2 = exp2f(fmaxf(s, 0.2f * s));
    s = eD.w + er4.w; wd3 = exp2f(fmaxf(s, 0.2f * s));
    if (!v1) { wb0 = wb1 = wb2 = wb3 = 0.f; }
    if (!v2) { wc0 = wc1 = wc2 = wc3 = 0.f; }
    if (!v3) { wd0 = wd1 = wd2 = wd3 = 0.f; }
    d0 += wa0 + wb0 + wc0 + wd0;
    d1 += wa1 + wb1 + wc1 + wd1;
    d2 += wa2 + wb2 + wc2 + wd2;
    d3 += wa3 + wb3 + wc3 + wd3;
    __half2 h0, h1, h2, h3;
    h0 = __float2half2_rn(wa0); h1 = __float2half2_rn(wa1);
    h2 = __float2half2_rn(wa2); h3 = __float2half2_rn(wa3);
    A0 = __hfma2(w2h(u0a.x), h0, A0); A1 = __hfma2(w2h(u0a.y), h1, A1);
    A2 = __hfma2(w2h(u0a.z), h2, A2); A3 = __hfma2(w2h(u0a.w), h3, A3);
    B0 = __hfma2(w2h(u0b.x), h0, B0); B1 = __hfma2(w2h(u0b.y), h1, B1);
    B2 = __hfma2(w2h(u0b.z), h2, B2); B3 = __hfma2(w2h(u0b.w), h3, B3);
    h0 = __float2half2_rn(wb0); h1 = __float2half2_rn(wb1);
    h2 = __float2half2_rn(wb2); h3 = __float2half2_rn(wb3);
    A0 = __hfma2(w2h(u1a.x), h0, A0); A1 = __hfma2(w2h(u1a.y), h1, A1);
    A2 = __hfma2(w2h(u1a.z), h2, A2); A3 = __hfma2(w2h(u1a.w), h3, A3);
    B0 = __hfma2(w2h(u1b.x), h0, B0); B1 = __hfma2(w2h(u1b.y), h1, B1);
    B2 = __hfma2(w2h(u1b.z), h2, B2); B3 = __hfma2(w2h(u1b.w), h3, B3);
    h0 = __float2half2_rn(wc0); h1 = __float2half2_rn(wc1);
    h2 = __float2half2_rn(wc2); h3 = __float2half2_rn(wc3);
    A0 = __hfma2(w2h(u2a.x), h0, A0); A1 = __hfma2(w2h(u2a.y), h1, A1);
    A2 = __hfma2(w2h(u2a.z), h2, A2); A3 = __hfma2(w2h(u2a.w), h3, A3);
    B0 = __hfma2(w2h(u2b.x), h0, B0); B1 = __hfma2(w2h(u2b.y), h1, B1);
    B2 = __hfma2(w2h(u2b.z), h2, B2); B3 = __hfma2(w2h(u2b.w), h3, B3);
    h0 = __float2half2_rn(wd0); h1 = __float2half2_rn(wd1);
    h2 = __float2half2_rn(wd2); h3 = __float2half2_rn(wd3);
    A0 = __hfma2(w2h(u3a.x), h0, A0); A1 = __hfma2(w2h(u3a.y), h1, A1);
    A2 = __hfma2(w2h(u3a.z), h2, A2); A3 = __hfma2(w2h(u3a.w), h3, A3);
    B0 = __hfma2(w2h(u3b.x), h0, B0); B1 = __hfma2(w2h(u3b.y), h1, B1);
    B2 = __hfma2(w2h(u3b.z), h2, B2); B3 = __hfma2(w2h(u3b.w), h3, B3);
  }
  __half2 i0 = __float2half2_rn((c > 0) ? 1.f / d0 : 0.f);
  __half2 i1 = __float2half2_rn((c > 0) ? 1.f / d1 : 0.f);
  __half2 i2 = __float2half2_rn((c > 0) ? 1.f / d2 : 0.f);
  __half2 i3 = __float2half2_rn((c > 0) ? 1.f / d3 : 0.f);
  uint4 oA, oB;
  oA.x = h2w(__hmul2(A0, i0)); oA.y = h2w(__hmul2(A1, i1));
  oA.z = h2w(__hmul2(A2, i2)); oA.w = h2w(__hmul2(A3, i3));
  oB.x = h2w(__hmul2(B0, i0)); oB.y = h2w(__hmul2(B1, i1));
  oB.z = h2w(__hmul2(B2, i2)); oB.w = h2w(__hmul2(B3, i3));
  int nl = pidl >> 1;                          // local node row 0..15
  *(uint4*)&Al[nl * 264 + slot * 128 + l7 * 16] = oA;
  *(uint4*)&Al[nl * 264 + slot * 128 + l7 * 16 + 8] = oB;
  __syncthreads();
  if (wave >= 2) return;                       // no further barriers

  // ---- merge: out[16 x 32] = Al(f16) @ WmT^T + bm; wave w does cols w*16.. ----
  int l15 = lane & 15, lk = (lane >> 4) * 8;
  f32x4 acc = {0.f, 0.f, 0.f, 0.f};
#pragma unroll
  for (int kt = 0; kt < 8; ++kt) {
    half8 a = *(const half8*)&Al[l15 * 264 + kt * 32 + lk];
    half8 b = *(const half8*)(const void*)(WmT + (size_t)(wave * 16 + l15) * 256 + kt * 32 + lk);
    acc = __builtin_amdgcn_mfma_f32_16x16x32_f16(a, b, acc, 0, 0, 0);
  }
  float bmv = bm[wave * 16 + l15];
#pragma unroll
  for (int r = 0; r < 4; ++r) {
    int row = blockIdx.x * 16 + (lane >> 4) * 4 + r;
    out[(size_t)row * 32 + wave * 16 + l15] = acc[r] + bmv;
  }
}

extern "C" void kernel_launch(void* const* d_in, const int* in_sizes, int n_in,
                              void* d_out, int out_size, void* d_ws, size_t ws_size,
                              hipStream_t stream)
{
  const float* feat = (const float*)d_in[0];
  const int*   src  = (const int*)d_in[1];
  const int*   dst  = (const int*)d_in[2];
  const float* W    = (const float*)d_in[4];
  const float* al   = (const float*)d_in[5];
  const float* ar   = (const float*)d_in[6];
  const float* Wm   = (const float*)d_in[7];
  const float* bm   = (const float*)d_in[8];
  float* out = (float*)d_out;
  (void)in_sizes; (void)n_in; (void)out_size; (void)ws_size;

  char* w = (char*)d_ws;
  size_t o = 0;
  auto take = [&](size_t bytes) -> void* {
    void* p = w + o;
    o += (bytes + 255) & ~(size_t)255;
    return p;
  };
  unsigned short* Btg = (unsigned short*)take((size_t)N_T * TILE_E * 2);         // 147 KB
  unsigned short* WmT = (unsigned short*)take((size_t)32 * 256 * 2);             // 16 KB
  unsigned short* ftg = (unsigned short*)take((size_t)N_T * N_NODES * HF * 2);   // 102.4 MB
  float* elg   = (float*)take((size_t)N_T * N_NODES * 4 * 4);                    // 6.4 MB
  float* erg   = (float*)take((size_t)N_T * N_NODES * 4 * 4);                    // 6.4 MB
  int*   cntb  = (int*)take((size_t)TN * 4);                                     // 1.6 MB
  int*   ofs   = (int*)take((size_t)TN * 4);
  int*   bsum  = (int*)take(4096);
  int*   rank  = (int*)take((size_t)TE * 4);                                     // 8 MB
  int*   bkt   = (int*)take((size_t)TE * 4);                                     // 8 MB

  hipMemsetAsync(cntb, 0, (size_t)TN * 4, stream);

  k_prep<<<34, 256, 0, stream>>>(W, al, ar, Wm, Btg, WmT);
  k_proj<<<1563, 256, 0, stream>>>(feat, Btg, ftg, elg, erg);
  k_hist<<<(TE + 255) / 256, 256, 0, stream>>>(dst, cntb, rank);
  k_scan1<<<NB1, 256, 0, stream>>>(cntb, ofs, bsum);
  k_scan2<<<1, 512, 0, stream>>>(bsum);
  k_scatter<<<(TE + 255) / 256, 256, 0, stream>>>(src, dst, ofs, bsum, rank, bkt);
  k_gathermerge<<<6250, 256, 0, stream>>>(bkt, ofs, cntb, bsum, elg, erg,
                                          (const uint4*)ftg, WmT, bm, out);
}

// Round 17
// 177.864 us; speedup vs baseline: 1.1899x; 1.0555x over previous
//
#include <hip/hip_runtime.h>
#include <hip/hip_fp16.h>

typedef short short8 __attribute__((ext_vector_type(8)));
typedef _Float16 half8 __attribute__((ext_vector_type(8)));
typedef float f32x4 __attribute__((ext_vector_type(4)));

#define N_NODES 100000
#define N_A     50000
#define N_EDGES 500000
#define N_T     4
#define D_IN    128
#define HF      128
#define BCOLS   144                  // 128 ft cols + 4 el + 4 er + 8 zero pad
#define TN      (N_T * N_NODES)
#define TE      (N_T * N_EDGES)
#define NB1     ((TN + 1023) / 1024) // 391 scan blocks
#define TILE_E  (BCOLS * D_IN)       // 18432 elems = 36864 B per (t) B-tile
#define LOG2E   1.44269504088896340736f
#define RSU     136                  // ft row stride in ushorts: 128 f16 + 4 f32 el (272 B)
#define RSV     17                   // ft row stride in uint4

__device__ __forceinline__ unsigned short f2b(float f) {
  unsigned int u = __float_as_uint(f);
  u += 0x7FFFu + ((u >> 16) & 1u);
  return (unsigned short)(u >> 16);
}
// f32 pair -> packed f16 word (v_cvt_pkrtz_f16_f32, 1 instruction)
__device__ __forceinline__ unsigned int pkh(float lo, float hi) {
  auto v = __builtin_amdgcn_cvt_pkrtz(lo, hi);
  unsigned int u; __builtin_memcpy(&u, &v, 4); return u;
}
__device__ __forceinline__ unsigned short f2h(float f) {
  auto v = __builtin_amdgcn_cvt_pkrtz(f, 0.f);
  unsigned int u; __builtin_memcpy(&u, &v, 4); return (unsigned short)(u & 0xFFFFu);
}
__device__ __forceinline__ __half2 w2h(unsigned int u) {
  __half2 h; __builtin_memcpy(&h, &u, 4); return h;
}
__device__ __forceinline__ unsigned int h2w(__half2 h) {
  unsigned int u; __builtin_memcpy(&u, &h, 4); return u;
}

// K0: fused prep + cnt zeroing. Blocks 0-1: Bt[t][144][128] bf16 swizzled,
// attn rows pre-scaled by log2e. Blocks 2-33: WmT f16 (permuted-k).
// All 34 blocks: grid-stride zero of cnt (replaces a memset dispatch).
__global__ __launch_bounds__(256) void k_prep(const float* __restrict__ W,
    const float* __restrict__ al, const float* __restrict__ ar,
    const float* __restrict__ Wm,
    unsigned short* __restrict__ Bt, unsigned short* __restrict__ WmT,
    int* __restrict__ cnt)
{
  if (blockIdx.x < 2) {
    int idx = blockIdx.x * 256 + threadIdx.x;
    int t = idx >> 7, k = idx & 127;
    const float* Wr = W + ((size_t)t * D_IN + k) * HF;
    unsigned short* o = Bt + (size_t)t * TILE_E;
    for (int j = 0; j < HF; ++j)
      o[(j * D_IN + k) ^ ((j & 7) << 3)] = f2b(Wr[j]);
    for (int h = 0; h < 4; ++h) {
      float sl = 0.f, sr = 0.f;
      const float* alh = al + (t * 4 + h) * 32;
      const float* arh = ar + (t * 4 + h) * 32;
      for (int f = 0; f < 32; ++f) { float w = Wr[h * 32 + f]; sl += w * alh[f]; sr += w * arh[f]; }
      int jl = 128 + h, jr = 132 + h;
      o[(jl * D_IN + k) ^ ((jl & 7) << 3)] = f2b(sl * LOG2E);
      o[(jr * D_IN + k) ^ ((jr & 7) << 3)] = f2b(sr * LOG2E);
    }
    for (int j = 136; j < 144; ++j)
      o[(j * D_IN + k) ^ ((j & 7) << 3)] = 0;
  } else {
    int idx = (blockIdx.x - 2) * 256 + threadIdx.x;
    int kidx = idx >> 5, j = idx & 31;
    int slot = kidx >> 7, p = kidx & 127;
    int col = (p & 7) * 16 + (p >> 3);
    WmT[j * 256 + kidx] = f2h(Wm[(slot * 128 + col) * 32 + j]);
  }
  // grid-stride zero of cnt
  for (int i = blockIdx.x * 256 + threadIdx.x; i < TN; i += 34 * 256)
    cnt[i] = 0;
}

// K1: projection GEMM (proven shape). Block = 64 rows (4 waves x 16),
// grid 1563, launch_bounds(256,4). ft rows 272 B: [128 f16 | 4 f32 el].
__global__ __launch_bounds__(256, 4) void k_proj(const float* __restrict__ feat,
    const unsigned short* __restrict__ Btg,
    unsigned short* __restrict__ ftg,
    float* __restrict__ erg)
{
  __shared__ __align__(16) unsigned short Bs[TILE_E];      // 36.8 KB -> 4 blocks/CU
  const int tid = threadIdx.x;
  const int wave = tid >> 6, lane = tid & 63;
  const int l15 = lane & 15, g = lane >> 4;
  const int wrow0 = blockIdx.x * 64 + wave * 16;

  short8 a[4];
  {
    int row = wrow0 + l15;
    const float* fr = feat + (size_t)(row < N_NODES ? row : N_NODES - 1) * D_IN;
#pragma unroll
    for (int kt = 0; kt < 4; ++kt) {
      float4 v0 = *(const float4*)(fr + kt * 32 + g * 8);
      float4 v1 = *(const float4*)(fr + kt * 32 + g * 8 + 4);
      short8 s;
      s[0] = (short)f2b(v0.x); s[1] = (short)f2b(v0.y);
      s[2] = (short)f2b(v0.z); s[3] = (short)f2b(v0.w);
      s[4] = (short)f2b(v1.x); s[5] = (short)f2b(v1.y);
      s[6] = (short)f2b(v1.z); s[7] = (short)f2b(v1.w);
      a[kt] = s;
    }
  }

  for (int t = 0; t < N_T; ++t) {
    if (t > 0) __syncthreads();
    {
      const uint4* src = (const uint4*)(Btg + (size_t)t * TILE_E);
      uint4* dstv = (uint4*)Bs;
#pragma unroll
      for (int i = 0; i < 9; ++i)
        dstv[i * 256 + tid] = src[i * 256 + tid];
    }
    __syncthreads();

    f32x4 acc[8];
#pragma unroll
    for (int ct = 0; ct < 8; ++ct) {
      f32x4 c = {0.f, 0.f, 0.f, 0.f};
#pragma unroll
      for (int kt = 0; kt < 4; ++kt) {
        int row = ct * 16 + l15;
        int boff = (row * 256 + kt * 64 + g * 16) ^ ((l15 & 7) << 4);
        short8 b = *(const short8*)((const char*)Bs + boff);
        c = __builtin_amdgcn_mfma_f32_16x16x32_bf16(a[kt], b, c, 0, 0, 0);
      }
      acc[ct] = c;
    }
    {
      f32x4 c8 = {0.f, 0.f, 0.f, 0.f};
#pragma unroll
      for (int kt = 0; kt < 4; ++kt) {
        int row = 128 + l15;
        int boff = (row * 256 + kt * 64 + g * 16) ^ ((l15 & 7) << 4);
        short8 b = *(const short8*)((const char*)Bs + boff);
        c8 = __builtin_amdgcn_mfma_f32_16x16x32_bf16(a[kt], b, c8, 0, 0, 0);
      }
      if (l15 < 8) {
#pragma unroll
        for (int r = 0; r < 4; ++r) {
          int row = wrow0 + g * 4 + r;
          if (row < N_NODES) {
            float v = c8[r];
            if (l15 < 4)
              *(float*)(ftg + (size_t)(t * N_NODES + row) * RSU + 128 + l15 * 2) = v;
            else
              erg[((size_t)t * N_NODES + row) * 4 + (l15 - 4)] = v;
          }
        }
      }
    }
    // direct permuted ft store (F16): row-position p = l15*8 + ct
#pragma unroll
    for (int r = 0; r < 4; ++r) {
      int row = wrow0 + g * 4 + r;
      if (row < N_NODES) {
        uint4 o;
        o.x = pkh(acc[0][r], acc[1][r]);
        o.y = pkh(acc[2][r], acc[3][r]);
        o.z = pkh(acc[4][r], acc[5][r]);
        o.w = pkh(acc[6][r], acc[7][r]);
        *(uint4*)(ftg + (size_t)(t * N_NODES + row) * RSU + l15 * 8) = o;
      }
    }
  }
}

// K2: histogram of kept edges by (t,dst) + per-edge within-bucket rank
__global__ __launch_bounds__(256) void k_hist(const int* __restrict__ dst,
    int* __restrict__ cnt, int* __restrict__ rank) {
  int idx = blockIdx.x * 256 + threadIdx.x;
  if (idx >= TE) return;
  int t = idx / N_EDGES;
  int d = dst[idx];
  bool keep = (t < 2) ? (d < N_A) : (d >= N_A);
  if (keep) rank[idx] = atomicAdd(&cnt[t * N_NODES + d], 1);
}

__global__ __launch_bounds__(256) void k_scan1(const int* __restrict__ cnt,
    int* __restrict__ ofs, int* __restrict__ bsum) {
  __shared__ int ts[256];
  int b = blockIdx.x, t = threadIdx.x;
  int base = b * 1024 + t * 4;
  int v0 = 0, v1 = 0, v2 = 0, v3 = 0;
  if (base + 0 < TN) v0 = cnt[base + 0];
  if (base + 1 < TN) v1 = cnt[base + 1];
  if (base + 2 < TN) v2 = cnt[base + 2];
  if (base + 3 < TN) v3 = cnt[base + 3];
  int s = v0 + v1 + v2 + v3;
  ts[t] = s;
  __syncthreads();
  for (int o = 1; o < 256; o <<= 1) {
    int x = (t >= o) ? ts[t - o] : 0;
    __syncthreads();
    ts[t] += x;
    __syncthreads();
  }
  int run = ts[t] - s;
  if (base + 0 < TN) ofs[base + 0] = run; run += v0;
  if (base + 1 < TN) ofs[base + 1] = run; run += v1;
  if (base + 2 < TN) ofs[base + 2] = run; run += v2;
  if (base + 3 < TN) ofs[base + 3] = run;
  if (t == 255) bsum[b] = ts[255];
}

__global__ __launch_bounds__(512) void k_scan2(int* __restrict__ bsum) {
  __shared__ int ts[512];
  int t = threadIdx.x;
  int v = (t < NB1) ? bsum[t] : 0;
  ts[t] = v;
  __syncthreads();
  for (int o = 1; o < 512; o <<= 1) {
    int x = (t >= o) ? ts[t - o] : 0;
    __syncthreads();
    ts[t] += x;
    __syncthreads();
  }
  if (t < NB1) bsum[t] = ts[t] - v;
}

// K3: slim scatter: 4 B record = src ft-row index; position from ofs+bsum+rank.
__global__ __launch_bounds__(256) void k_scatter(const int* __restrict__ src, const int* __restrict__ dst,
    const int* __restrict__ ofs, const int* __restrict__ bsum, const int* __restrict__ rank,
    int* __restrict__ bkt) {
  int idx = blockIdx.x * 256 + threadIdx.x;
  if (idx >= TE) return;
  int t = idx / N_EDGES;
  int d = dst[idx];
  bool keep = (t < 2) ? (d < N_A) : (d >= N_A);
  if (!keep) return;
  int key = t * N_NODES + d;
  int p = ofs[key] + bsum[key >> 10] + rank[idx];
  bkt[p] = t * N_NODES + src[idx];
}

// K4: FUSED gather + merge. Block = 4 waves x 8 pairs = 16 consecutive nodes.
// Per edge ALL data comes from one 272 B ft row: u_a(16B)+u_b(16B)+el4(16B).
// Masked unroll-4; f16 __hfma2 accum; 16x264 LDS tile; waves 0-1 do the
// 16x256x32 merge MFMA from L2-resident WmT and store out directly.
__global__ __launch_bounds__(256) void k_gathermerge(const int* __restrict__ bkt,
    const int* __restrict__ ofs, const int* __restrict__ cnt, const int* __restrict__ bsum,
    const float* __restrict__ erg,
    const uint4* __restrict__ ftu,
    const unsigned short* __restrict__ WmT, const float* __restrict__ bm,
    float* __restrict__ out)
{
  __shared__ __align__(16) unsigned short Al[16 * 264];    // 8.4 KB
  int tid = threadIdx.x;
  int wave = tid >> 6, lane = tid & 63;
  int g8 = lane >> 3, l7 = lane & 7;
  int pidl = wave * 8 + g8;                    // local pair 0..31
  int pid = blockIdx.x * 32 + pidl;            // pair id = node*2 + slot
  int n = pid >> 1, slot = pid & 1;
  int t = slot + ((n >= N_A) ? 2 : 0);
  int key = t * N_NODES + n;
  int base = ofs[key] + bsum[key >> 10];
  int c = cnt[key];
  float4 er4 = *(const float4*)(erg + (size_t)key * 4);
  __half2 A0 = __float2half2_rn(0.f), A1 = A0, A2 = A0, A3 = A0;
  __half2 B0 = A0, B1 = A0, B2 = A0, B3 = A0;
  float d0 = 0.f, d1 = 0.f, d2 = 0.f, d3 = 0.f;
  int qb = l7 * 2;
  for (int i = 0; i < c; i += 4) {
    bool v1 = i + 1 < c, v2 = i + 2 < c, v3 = i + 3 < c;
    int e0 = base + i;
    int e1 = base + (v1 ? i + 1 : i);
    int e2 = base + (v2 ? i + 2 : i);
    int e3 = base + (v3 ? i + 3 : i);
    int s0 = bkt[e0], s1 = bkt[e1], s2 = bkt[e2], s3 = bkt[e3];
    const uint4* r0 = ftu + (size_t)s0 * RSV;
    const uint4* r1 = ftu + (size_t)s1 * RSV;
    const uint4* r2 = ftu + (size_t)s2 * RSV;
    const uint4* r3 = ftu + (size_t)s3 * RSV;
    float4 eA = *(const float4*)(r0 + 16);
    float4 eB = *(const float4*)(r1 + 16);
    float4 eC = *(const float4*)(r2 + 16);
    float4 eD = *(const float4*)(r3 + 16);
    uint4 u0a = r0[qb], u0b = r0[qb + 1];
    uint4 u1a = r1[qb], u1b = r1[qb + 1];
    uint4 u2a = r2[qb], u2b = r2[qb + 1];
    uint4 u3a = r3[qb], u3b = r3[qb + 1];
    float s;
    float wa0, wa1, wa2, wa3, wb0, wb1, wb2, wb3;
    float wc0, wc1, wc2, wc3, wd0, wd1, wd2, wd3;
    s = eA.x + er4.x; wa0 = exp2f(fmaxf(s, 0.2f * s));
    s = eA.y + er4.y; wa1 = exp2f(fmaxf(s, 0.2f * s));
    s = eA.z + er4.z; wa2 = exp2f(fmaxf(s, 0.2f * s));
    s = eA.w + er4.w; wa3 = exp2f(fmaxf(s, 0.2f * s));
    s = eB.x + er4.x; wb0 = exp2f(fmaxf(s, 0.2f * s));
    s = eB.y + er4.y; wb1 = exp2f(fmaxf(s, 0.2f * s));
    s = eB.z + er4.z; wb2 = exp2f(fmaxf(s, 0.2f * s));
    s = eB.w + er4.w; wb3 = exp2f(fmaxf(s, 0.2f * s));
    s = eC.x + er4.x; wc0 = exp2f(fmaxf(s, 0.2f * s));
    s = eC.y + er4.y; wc1 = exp2f(fmaxf(s, 0.2f * s));
    s = eC.z + er4.z; wc2 = exp2f(fmaxf(s, 0.2f * s));
    s = eC.w + er4.w; wc3 = exp2f(fmaxf(s, 0.2f * s));
    s = eD.x + er4.x; wd0 = exp2f(fmaxf(s, 0.2f * s));
    s = eD.y + er4.y; wd1 = exp2f(fmaxf(s, 0.2f * s));
    s = eD.z + er4.z; wd2 = exp2f(fmaxf(s, 0.2f * s));
    s = eD.w + er4.w; wd3 = exp2f(fmaxf(s, 0.2f * s));
    if (!v1) { wb0 = wb1 = wb2 = wb3 = 0.f; }
    if (!v2) { wc0 = wc1 = wc2 = wc3 = 0.f; }
    if (!v3) { wd0 = wd1 = wd2 = wd3 = 0.f; }
    d0 += wa0 + wb0 + wc0 + wd0;
    d1 += wa1 + wb1 + wc1 + wd1;
    d2 += wa2 + wb2 + wc2 + wd2;
    d3 += wa3 + wb3 + wc3 + wd3;
    __half2 h0, h1, h2, h3;
    h0 = __float2half2_rn(wa0); h1 = __float2half2_rn(wa1);
    h2 = __float2half2_rn(wa2); h3 = __float2half2_rn(wa3);
    A0 = __hfma2(w2h(u0a.x), h0, A0); A1 = __hfma2(w2h(u0a.y), h1, A1);
    A2 = __hfma2(w2h(u0a.z), h2, A2); A3 = __hfma2(w2h(u0a.w), h3, A3);
    B0 = __hfma2(w2h(u0b.x), h0, B0); B1 = __hfma2(w2h(u0b.y), h1, B1);
    B2 = __hfma2(w2h(u0b.z), h2, B2); B3 = __hfma2(w2h(u0b.w), h3, B3);
    h0 = __float2half2_rn(wb0); h1 = __float2half2_rn(wb1);
    h2 = __float2half2_rn(wb2); h3 = __float2half2_rn(wb3);
    A0 = __hfma2(w2h(u1a.x), h0, A0); A1 = __hfma2(w2h(u1a.y), h1, A1);
    A2 = __hfma2(w2h(u1a.z), h2, A2); A3 = __hfma2(w2h(u1a.w), h3, A3);
    B0 = __hfma2(w2h(u1b.x), h0, B0); B1 = __hfma2(w2h(u1b.y), h1, B1);
    B2 = __hfma2(w2h(u1b.z), h2, B2); B3 = __hfma2(w2h(u1b.w), h3, B3);
    h0 = __float2half2_rn(wc0); h1 = __float2half2_rn(wc1);
    h2 = __float2half2_rn(wc2); h3 = __float2half2_rn(wc3);
    A0 = __hfma2(w2h(u2a.x), h0, A0); A1 = __hfma2(w2h(u2a.y), h1, A1);
    A2 = __hfma2(w2h(u2a.z), h2, A2); A3 = __hfma2(w2h(u2a.w), h3, A3);
    B0 = __hfma2(w2h(u2b.x), h0, B0); B1 = __hfma2(w2h(u2b.y), h1, B1);
    B2 = __hfma2(w2h(u2b.z), h2, B2); B3 = __hfma2(w2h(u2b.w), h3, B3);
    h0 = __float2half2_rn(wd0); h1 = __float2half2_rn(wd1);
    h2 = __float2half2_rn(wd2); h3 = __float2half2_rn(wd3);
    A0 = __hfma2(w2h(u3a.x), h0, A0); A1 = __hfma2(w2h(u3a.y), h1, A1);
    A2 = __hfma2(w2h(u3a.z), h2, A2); A3 = __hfma2(w2h(u3a.w), h3, A3);
    B0 = __hfma2(w2h(u3b.x), h0, B0); B1 = __hfma2(w2h(u3b.y), h1, B1);
    B2 = __hfma2(w2h(u3b.z), h2, B2); B3 = __hfma2(w2h(u3b.w), h3, B3);
  }
  __half2 i0 = __float2half2_rn((c > 0) ? 1.f / d0 : 0.f);
  __half2 i1 = __float2half2_rn((c > 0) ? 1.f / d1 : 0.f);
  __half2 i2 = __float2half2_rn((c > 0) ? 1.f / d2 : 0.f);
  __half2 i3 = __float2half2_rn((c > 0) ? 1.f / d3 : 0.f);
  uint4 oA, oB;
  oA.x = h2w(__hmul2(A0, i0)); oA.y = h2w(__hmul2(A1, i1));
  oA.z = h2w(__hmul2(A2, i2)); oA.w = h2w(__hmul2(A3, i3));
  oB.x = h2w(__hmul2(B0, i0)); oB.y = h2w(__hmul2(B1, i1));
  oB.z = h2w(__hmul2(B2, i2)); oB.w = h2w(__hmul2(B3, i3));
  int nl = pidl >> 1;                          // local node row 0..15
  *(uint4*)&Al[nl * 264 + slot * 128 + l7 * 16] = oA;
  *(uint4*)&Al[nl * 264 + slot * 128 + l7 * 16 + 8] = oB;
  __syncthreads();
  if (wave >= 2) return;                       // no further barriers

  // ---- merge: out[16 x 32] = Al(f16) @ WmT^T + bm; wave w does cols w*16.. ----
  int l15 = lane & 15, lk = (lane >> 4) * 8;
  f32x4 acc = {0.f, 0.f, 0.f, 0.f};
#pragma unroll
  for (int kt = 0; kt < 8; ++kt) {
    half8 a = *(const half8*)&Al[l15 * 264 + kt * 32 + lk];
    half8 b = *(const half8*)(const void*)(WmT + (size_t)(wave * 16 + l15) * 256 + kt * 32 + lk);
    acc = __builtin_amdgcn_mfma_f32_16x16x32_f16(a, b, acc, 0, 0, 0);
  }
  float bmv = bm[wave * 16 + l15];
#pragma unroll
  for (int r = 0; r < 4; ++r) {
    int row = blockIdx.x * 16 + (lane >> 4) * 4 + r;
    out[(size_t)row * 32 + wave * 16 + l15] = acc[r] + bmv;
  }
}

extern "C" void kernel_launch(void* const* d_in, const int* in_sizes, int n_in,
                              void* d_out, int out_size, void* d_ws, size_t ws_size,
                              hipStream_t stream)
{
  const float* feat = (const float*)d_in[0];
  const int*   src  = (const int*)d_in[1];
  const int*   dst  = (const int*)d_in[2];
  const float* W    = (const float*)d_in[4];
  const float* al   = (const float*)d_in[5];
  const float* ar   = (const float*)d_in[6];
  const float* Wm   = (const float*)d_in[7];
  const float* bm   = (const float*)d_in[8];
  float* out = (float*)d_out;
  (void)in_sizes; (void)n_in; (void)out_size; (void)ws_size;

  char* w = (char*)d_ws;
  size_t o = 0;
  auto take = [&](size_t bytes) -> void* {
    void* p = w + o;
    o += (bytes + 255) & ~(size_t)255;
    return p;
  };
  unsigned short* Btg = (unsigned short*)take((size_t)N_T * TILE_E * 2);         // 147 KB
  unsigned short* WmT = (unsigned short*)take((size_t)32 * 256 * 2);             // 16 KB
  unsigned short* ftg = (unsigned short*)take((size_t)TN * RSU * 2);             // 108.8 MB
  float* erg   = (float*)take((size_t)TN * 4 * 4);                               // 6.4 MB
  int*   cntb  = (int*)take((size_t)TN * 4);                                     // 1.6 MB
  int*   ofs   = (int*)take((size_t)TN * 4);
  int*   bsum  = (int*)take(4096);
  int*   rank  = (int*)take((size_t)TE * 4);                                     // 8 MB
  int*   bkt   = (int*)take((size_t)TE * 4);                                     // 8 MB

  k_prep<<<34, 256, 0, stream>>>(W, al, ar, Wm, Btg, WmT, cntb);
  k_proj<<<1563, 256, 0, stream>>>(feat, Btg, ftg, erg);
  k_hist<<<(TE + 255) / 256, 256, 0, stream>>>(dst, cntb, rank);
  k_scan1<<<NB1, 256, 0, stream>>>(cntb, ofs, bsum);
  k_scan2<<<1, 512, 0, stream>>>(bsum);
  k_scatter<<<(TE + 255) / 256, 256, 0, stream>>>(src, dst, ofs, bsum, rank, bkt);
  k_gathermerge<<<6250, 256, 0, stream>>>(bkt, ofs, cntb, bsum, erg,
                                          (const uint4*)ftg, WmT, bm, out);
}